// Round 11
// baseline (547.854 us; speedup 1.0000x reference)
//
#include <hip/hip_runtime.h>
#include <hip/hip_bf16.h>
#include <stdint.h>

typedef __attribute__((ext_vector_type(8))) __bf16 bf16x8;
typedef __attribute__((ext_vector_type(4))) float f32x4;

__device__ __forceinline__ float bf2f(unsigned short u) {
  unsigned int x = ((unsigned int)u) << 16;
  float f; __builtin_memcpy(&f, &x, 4); return f;
}
__device__ __forceinline__ unsigned short f2bf(float f) {
  unsigned int x; __builtin_memcpy(&x, &f, 4);
  unsigned int r = x + 0x7fffu + ((x >> 16) & 1u);
  return (unsigned short)(r >> 16);
}
// pack two fp32 -> two bf16 (RNE), low = a, high = b
__device__ __forceinline__ unsigned int pk2(float a, float b) {
  __hip_bfloat162 h = __float22bfloat162_rn(float2{a, b});
  unsigned int u; __builtin_memcpy(&u, &h, 4); return u;
}
__device__ __forceinline__ float fmax3(float a, float b, float c) {
  return fmaxf(fmaxf(a, b), c);  // clang fuses to v_max3_f32
}
// convert 8 consecutive fp32 to 8 bf16 packed in a uint4
__device__ __forceinline__ uint4 cvt8(const float* src) {
  float4 a = *(const float4*)src;
  float4 b = *(const float4*)(src + 4);
  uint4 r;
  r.x = pk2(a.x, a.y); r.y = pk2(a.z, a.w);
  r.z = pk2(b.x, b.y); r.w = pk2(b.z, b.w);
  return r;
}

// async global -> LDS, 16B per lane. LDS dest = wave-uniform base + lane*16.
__device__ __forceinline__ void gload_lds16(const unsigned short* g, unsigned short* l) {
  __builtin_amdgcn_global_load_lds(
      (const __attribute__((address_space(1))) void*)g,
      (__attribute__((address_space(3))) void*)l, 16, 0, 0);
}

// ---------------------------------------------------------------------------
// One-shot fp32 -> bf16 conversion: x (12582912), Wqkv (3145728), Wo (2359296)
// ---------------------------------------------------------------------------
__global__ __launch_bounds__(256) void cvt_all(const float* __restrict__ x,
                                               const float* __restrict__ wqkv,
                                               const float* __restrict__ wo,
                                               unsigned short* __restrict__ xb,
                                               unsigned short* __restrict__ wqkvb,
                                               unsigned short* __restrict__ wob) {
  long i = ((long)blockIdx.x * 256 + threadIdx.x) * 8;
  if (i < 12582912) { *(uint4*)(xb + i) = cvt8(x + i); return; }
  i -= 12582912;
  if (i < 3145728) { *(uint4*)(wqkvb + i) = cvt8(wqkv + i); return; }
  i -= 3145728;
  *(uint4*)(wob + i) = cvt8(wo + i);
}

// ---------------------------------------------------------------------------
// GEMM: C[M,N] = A[M,K] @ W[N,K]^T (+ bias[N]).  (verified rounds 2/4/8/9)
// ---------------------------------------------------------------------------
template <bool OUT_F32, bool HAS_BIAS>
__global__ __launch_bounds__(256) void gemm_bt(const unsigned short* __restrict__ A,
                                               const unsigned short* __restrict__ W,
                                               const float* __restrict__ bias,
                                               void* __restrict__ Cv,
                                               int M, int N, int K) {
  __shared__ __align__(16) unsigned short sA[128 * 32];
  __shared__ __align__(16) unsigned short sB[128 * 32];
  const int tid = threadIdx.x;
  const int lane = tid & 63;
  const int w = tid >> 6;
  const long m0 = (long)blockIdx.y * 128;
  const long n0 = (long)blockIdx.x * 128;
  const int wm = (w >> 1) * 64;
  const int wn = (w & 1) * 64;
  const int fr = lane & 15, fq = lane >> 4;

  const int srow = w * 16 + (lane >> 2);
  const int scol = (lane & 3) * 8;
  const unsigned short* Ag = A + m0 * K + (long)srow * K + scol;
  const unsigned short* Wg = W + n0 * K + (long)srow * K + scol;
  const long rstep = 64L * K;
  unsigned short* sAw = sA + w * 512;
  unsigned short* sBw = sB + w * 512;

  f32x4 acc[4][4];
#pragma unroll
  for (int i = 0; i < 4; ++i)
#pragma unroll
    for (int j = 0; j < 4; ++j) acc[i][j] = f32x4{0.f, 0.f, 0.f, 0.f};

  for (int k0 = 0; k0 < K; k0 += 32) {
    __syncthreads();
    gload_lds16(Ag + k0,         sAw);
    gload_lds16(Ag + rstep + k0, sAw + 2048);
    gload_lds16(Wg + k0,         sBw);
    gload_lds16(Wg + rstep + k0, sBw + 2048);
    __syncthreads();
    bf16x8 af[4], bfr[4];
#pragma unroll
    for (int t = 0; t < 4; ++t) {
      af[t]  = *(const bf16x8*)&sA[(wm + t * 16 + fr) * 32 + fq * 8];
      bfr[t] = *(const bf16x8*)&sB[(wn + t * 16 + fr) * 32 + fq * 8];
    }
#pragma unroll
    for (int mt = 0; mt < 4; ++mt)
#pragma unroll
      for (int nt = 0; nt < 4; ++nt)
        acc[mt][nt] = __builtin_amdgcn_mfma_f32_16x16x32_bf16(af[mt], bfr[nt], acc[mt][nt], 0, 0, 0);
  }

#pragma unroll
  for (int nt = 0; nt < 4; ++nt) {
    long n = n0 + wn + nt * 16 + fr;
    float bv = HAS_BIAS ? bias[n] : 0.f;
#pragma unroll
    for (int mt = 0; mt < 4; ++mt)
#pragma unroll
      for (int r = 0; r < 4; ++r) {
        long m = m0 + wm + mt * 16 + fq * 4 + r;
        float v = acc[mt][nt][r] + bv;
        if (OUT_F32)
          ((float*)Cv)[m * N + n] = v;
        else
          ((unsigned short*)Cv)[m * N + n] = f2bf(v);
      }
  }
}

// ---------------------------------------------------------------------------
// RoPE (in-place on bf16 qkv_ws) + fp32 KV cache scatter + bf16 V^T write.
// (verified round 8/9)
// ---------------------------------------------------------------------------
__global__ __launch_bounds__(256) void rope_scatter(unsigned short* __restrict__ qkv,
                                                    const float* __restrict__ cosb,
                                                    const float* __restrict__ sinb,
                                                    const int* __restrict__ slot_mapping,
                                                    float* __restrict__ kc,
                                                    float* __restrict__ vc,
                                                    unsigned short* __restrict__ vt) {
  const int u = blockIdx.x * 256 + threadIdx.x;
  if (u < 917504) {
    const int m = u / 112;
    const int g = u - m * 112;
    const int head = g >> 3;
    const int d0 = (g & 7) * 8;
    const int slot = slot_mapping[m];
    const size_t base = (size_t)m * 2048;
    const size_t cbase = (size_t)m * 128;
    const int off = head < 12 ? head * 128 : 1536 + (head - 12) * 128;

    union { uint4 q; unsigned short s[8]; } X1, X2, O1, O2;
    X1.q = *(const uint4*)(qkv + base + off + d0);
    X2.q = *(const uint4*)(qkv + base + off + d0 + 64);
    float c1[8], s1[8], c2[8], s2[8];
    *(float4*)&c1[0] = *(const float4*)(cosb + cbase + d0);
    *(float4*)&c1[4] = *(const float4*)(cosb + cbase + d0 + 4);
    *(float4*)&s1[0] = *(const float4*)(sinb + cbase + d0);
    *(float4*)&s1[4] = *(const float4*)(sinb + cbase + d0 + 4);
    *(float4*)&c2[0] = *(const float4*)(cosb + cbase + d0 + 64);
    *(float4*)&c2[4] = *(const float4*)(cosb + cbase + d0 + 68);
    *(float4*)&s2[0] = *(const float4*)(sinb + cbase + d0 + 64);
    *(float4*)&s2[4] = *(const float4*)(sinb + cbase + d0 + 68);

    float o1[8], o2[8];
#pragma unroll
    for (int j = 0; j < 8; ++j) {
      float x1 = bf2f(X1.s[j]), x2 = bf2f(X2.s[j]);
      o1[j] = x1 * c1[j] - x2 * s1[j];
      o2[j] = x2 * c2[j] + x1 * s2[j];
      O1.s[j] = f2bf(o1[j]);
      O2.s[j] = f2bf(o2[j]);
    }
    *(uint4*)(qkv + base + off + d0) = O1.q;
    *(uint4*)(qkv + base + off + d0 + 64) = O2.q;
    if (head >= 12) {
      float* kp = kc + (size_t)slot * 256 + (head - 12) * 128 + d0;
      *(float4*)(kp)      = *(const float4*)&o1[0];
      *(float4*)(kp + 4)  = *(const float4*)&o1[4];
      *(float4*)(kp + 64) = *(const float4*)&o2[0];
      *(float4*)(kp + 68) = *(const float4*)&o2[4];
    }
  } else {
    const int u2 = u - 917504;
    const int m = u2 & 8191;       // token (consecutive per lane -> coalesced)
    const int g = u2 >> 13;        // 0..31: kvh = g>>4, d0 = (g&15)*8
    const int slot = slot_mapping[m];
    union { uint4 q; unsigned short s[8]; } V;
    V.q = *(const uint4*)(qkv + (size_t)m * 2048 + 1792 + g * 8);
    float vo[8];
#pragma unroll
    for (int j = 0; j < 8; ++j) vo[j] = bf2f(V.s[j]);
    float* vp = vc + (size_t)slot * 256 + g * 8;
    *(float4*)(vp)     = *(const float4*)&vo[0];
    *(float4*)(vp + 4) = *(const float4*)&vo[4];
    // V^T for attention: row = (b*2+kvh)*128 + d, col = s (token within seq)
    const int kvh = g >> 4;
    const int d0 = (g & 15) * 8;
    unsigned short* vtp = vt + ((size_t)((m >> 11) * 2 + kvh) * 128 + d0) * 2048 + (m & 2047);
#pragma unroll
    for (int j = 0; j < 8; ++j) vtp[(size_t)j * 2048] = V.s[j];
  }
}

// ---------------------------------------------------------------------------
// Flash attention, causal, GQA. Swapped QK^T + V^T staging + q-pairing
// (verified r8/r9). Serial-chain cuts (this version, unmeasured):
//  * split process into qk/sm/storeP/pv; interleave A/B phases so B's softmax
//    (VALU) overlaps A's PV (MFMA+LDS) and hides storeP->pf latency.
//  * defer-max (THR=8): skip rescale + the 4-dependent-shfl al4 chain when
//    __all(mx <= m_i + 8) — bf16 relative precision is magnitude-invariant.
//  * packed P-store: 4x 8B writes instead of 16x ds_write_b16.
//  * max3 tree for row max; pairwise tree for row sum.
// ---------------------------------------------------------------------------
__global__ __launch_bounds__(256) void attn_kernel(const unsigned short* __restrict__ qkv,
                                                   const unsigned short* __restrict__ vt,
                                                   unsigned short* __restrict__ out) {
  const int qbA = blockIdx.x;       // 0..15
  const int qbB = 31 - qbA;         // 31..16
  const int h = blockIdx.y, b = blockIdx.z;
  const int kvh = h / 6;
  __shared__ __align__(16) unsigned short sK[2][64 * 128];
  __shared__ __align__(16) unsigned short sV[2][128 * 64];
  __shared__ __align__(16) unsigned short sP[4][16 * 72];
  const int tid = threadIdx.x, lane = tid & 63, w = tid >> 6;
  const int fr = lane & 15, fq = lane >> 4;
  const float scale = 0.08838834764831845f;
  const float LOG2E = 1.44269504089f;

  bf16x8 qfA[4], qfB[4];  // Q[q = w*16+fr][k = fq*8..+7]
  {
    const unsigned short* qpA =
        qkv + ((size_t)(b * 2048 + qbA * 64 + w * 16 + fr) * 2048 + h * 128 + fq * 8);
    const unsigned short* qpB =
        qkv + ((size_t)(b * 2048 + qbB * 64 + w * 16 + fr) * 2048 + h * 128 + fq * 8);
#pragma unroll
    for (int kt = 0; kt < 4; ++kt) {
      qfA[kt] = *(const bf16x8*)(qpA + kt * 32);
      qfB[kt] = *(const bf16x8*)(qpB + kt * 32);
    }
  }
  float mA = -3.0e38f, lA = 0.f, mB = -3.0e38f, lB = 0.f;
  f32x4 accA[8], accB[8];
#pragma unroll
  for (int i = 0; i < 8; ++i) {
    accA[i] = f32x4{0.f, 0.f, 0.f, 0.f};
    accB[i] = f32x4{0.f, 0.f, 0.f, 0.f};
  }

  auto stage_K = [&](int t, int buf) {
    const size_t tok0 = (size_t)(b * 2048 + t * 64);
#pragma unroll
    for (int i = 0; i < 4; ++i) {
      int c = i * 256 + w * 64 + lane;
      int kv = c >> 4, gp = c & 15;
      int g = gp ^ (kv & 7);
      gload_lds16(qkv + (tok0 + kv) * 2048 + 1536 + kvh * 128 + g * 8,
                  &sK[buf][0] + i * 2048 + w * 512);
    }
  };
  auto stage_VT = [&](int t, int buf) {
    const size_t rowbase = (size_t)((b * 2 + kvh) * 128);
#pragma unroll
    for (int i = 0; i < 4; ++i) {
      int c = i * 256 + w * 64 + lane;
      int d = c >> 3, gp = c & 7;
      int g = gp ^ (d & 7);
      gload_lds16(vt + (rowbase + d) * 2048 + t * 64 + g * 8,
                  &sV[buf][0] + i * 2048 + w * 512);
    }
  };

  // phase 1: QK^T (swapped) -> s4
  auto qk = [&](const bf16x8* qf, f32x4* s4, int cur) {
#pragma unroll
    for (int ntv = 0; ntv < 4; ++ntv) s4[ntv] = f32x4{0.f, 0.f, 0.f, 0.f};
    __builtin_amdgcn_s_setprio(1);
#pragma unroll
    for (int ntv = 0; ntv < 4; ++ntv) {
      int kvl = ntv * 16 + fr;
      int swz = kvl & 7;
#pragma unroll
      for (int kt = 0; kt < 4; ++kt) {
        bf16x8 kf = *(const bf16x8*)&sK[cur][kvl * 128 + ((kt * 4 + fq) ^ swz) * 8];
        s4[ntv] = __builtin_amdgcn_mfma_f32_16x16x32_bf16(kf, qf[kt], s4[ntv], 0, 0, 0);
      }
    }
    __builtin_amdgcn_s_setprio(0);
  };

  // phase 2: softmax (defer-max). pm out: P values for this lane's 16 kv slots
  auto sm = [&](const f32x4* s4, float& m_i, float& l_i, f32x4* accO,
                float (&pm)[4][4], bool diag) {
    float sc[4][4];
#pragma unroll
    for (int ntv = 0; ntv < 4; ++ntv)
#pragma unroll
      for (int r = 0; r < 4; ++r) {
        float v = s4[ntv][r] * scale;
        if (diag && (ntv * 16 + fq * 4 + r > w * 16 + fr)) v = -1e30f;
        sc[ntv][r] = v;
      }
    // row max via max3 tree (depth ~4)
    float p0 = fmax3(sc[0][0], sc[0][1], sc[0][2]);
    float p1 = fmax3(sc[0][3], sc[1][0], sc[1][1]);
    float p2 = fmax3(sc[1][2], sc[1][3], sc[2][0]);
    float p3 = fmax3(sc[2][1], sc[2][2], sc[2][3]);
    float p4 = fmax3(sc[3][0], sc[3][1], sc[3][2]);
    float mx = fmaxf(fmax3(p0, p1, p2), fmax3(p3, p4, sc[3][3]));
    mx = fmaxf(mx, __shfl_xor(mx, 16));
    mx = fmaxf(mx, __shfl_xor(mx, 32));
    // defer-max: skip rescale when the running max still bounds P by e^8
    const bool keep = __all(mx <= m_i + 8.0f);
    float al = 1.f;
    if (!keep) {
      float mnew = fmaxf(m_i, mx);
      al = exp2f((m_i - mnew) * LOG2E);
      m_i = mnew;
    }
    float rs4[4];
#pragma unroll
    for (int ntv = 0; ntv < 4; ++ntv) {
#pragma unroll
      for (int r = 0; r < 4; ++r) pm[ntv][r] = exp2f((sc[ntv][r] - m_i) * LOG2E);
      rs4[ntv] = (pm[ntv][0] + pm[ntv][1]) + (pm[ntv][2] + pm[ntv][3]);
    }
    float rs = (rs4[0] + rs4[1]) + (rs4[2] + rs4[3]);
    rs += __shfl_xor(rs, 16);
    rs += __shfl_xor(rs, 32);
    if (!keep) {
      float al4[4];
#pragma unroll
      for (int r = 0; r < 4; ++r) al4[r] = __shfl(al, fq * 4 + r);
#pragma unroll
      for (int n2 = 0; n2 < 8; ++n2)
#pragma unroll
        for (int r = 0; r < 4; ++r) accO[n2][r] *= al4[r];
      l_i = l_i * al + rs;
    } else {
      l_i = l_i + rs;
    }
  };

  // phase 3: packed P store (4x 8B instead of 16x 2B)
  auto store_p = [&](const float (&pm)[4][4]) {
#pragma unroll
    for (int ntv = 0; ntv < 4; ++ntv) {
      uint2 pkd;
      pkd.x = pk2(pm[ntv][0], pm[ntv][1]);
      pkd.y = pk2(pm[ntv][2], pm[ntv][3]);
      *(uint2*)&sP[w][fr * 72 + ntv * 16 + fq * 4] = pkd;
    }
  };

  // phase 4: PV
  auto pv = [&](f32x4* accO, int cur) {
    __builtin_amdgcn_s_setprio(1);
#pragma unroll
    for (int kt = 0; kt < 2; ++kt) {
      bf16x8 pf = *(const bf16x8*)&sP[w][fr * 72 + kt * 32 + fq * 8];
#pragma unroll
      for (int n2 = 0; n2 < 8; ++n2) {
        int d = n2 * 16 + fr;
        bf16x8 vf = *(const bf16x8*)&sV[cur][d * 64 + (((kt * 4 + fq) ^ (d & 7)) << 3)];
        accO[n2] = __builtin_amdgcn_mfma_f32_16x16x32_bf16(pf, vf, accO[n2], 0, 0, 0);
      }
    }
    __builtin_amdgcn_s_setprio(0);
  };

  stage_K(0, 0);
  stage_VT(0, 0);
  __syncthreads();  // drains DMA (vmcnt) before first reads

  for (int t = 0; t <= qbB; ++t) {
    const int cur = t & 1;
    if (t < qbB) {  // prefetch next tile while computing this one
      stage_K(t + 1, cur ^ 1);
      stage_VT(t + 1, cur ^ 1);
    }
    if (t <= qbA) {
      // both active: interleave so smB (VALU) overlaps pvA (MFMA+LDS)
      f32x4 s4A[4], s4B[4];
      float pmA[4][4], pmB[4][4];
      qk(qfA, s4A, cur);
      qk(qfB, s4B, cur);
      sm(s4A, mA, lA, accA, pmA, t == qbA);
      store_p(pmA);
      sm(s4B, mB, lB, accB, pmB, t == qbB);
      pv(accA, cur);
      store_p(pmB);   // same-wave LDS order: after pvA's pf reads
      pv(accB, cur);
    } else {
      f32x4 s4B[4];
      float pmB[4][4];
      qk(qfB, s4B, cur);
      sm(s4B, mB, lB, accB, pmB, t == qbB);
      store_p(pmB);
      pv(accB, cur);
    }
    if (t < qbB) __syncthreads();  // one barrier/tile; drains prefetch DMA
  }

  auto epilogue = [&](float l_i, const f32x4* accO, int qb) {
    float linv[4];
#pragma unroll
    for (int r = 0; r < 4; ++r) linv[r] = __shfl(l_i, fq * 4 + r);
#pragma unroll
    for (int r = 0; r < 4; ++r) {
      float inv = 1.f / linv[r];
      size_t row = (size_t)(b * 2048 + qb * 64 + w * 16 + fq * 4 + r);
#pragma unroll
      for (int n2 = 0; n2 < 8; ++n2)
        out[row * 1536 + h * 128 + n2 * 16 + fr] = f2bf(accO[n2][r] * inv);
    }
  };
  epilogue(lA, accA, qbA);
  epilogue(lB, accB, qbB);
}

// ---------------------------------------------------------------------------
extern "C" void kernel_launch(void* const* d_in, const int* in_sizes, int n_in,
                              void* d_out, int out_size, void* d_ws, size_t ws_size,
                              hipStream_t stream) {
  const float* x    = (const float*)d_in[0];
  const float* cosb = (const float*)d_in[1];
  const float* sinb = (const float*)d_in[2];
  const float* kci  = (const float*)d_in[3];
  const float* vci  = (const float*)d_in[4];
  const int* slot   = (const int*)d_in[5];
  const float* Wqkv = (const float*)d_in[6];
  const float* bqkv = (const float*)d_in[7];
  const float* Wo   = (const float*)d_in[8];

  float* out = (float*)d_out;
  float* kc  = out + (size_t)12582912;   // 4*2048*1536
  float* vc  = kc + (size_t)4194304;     // 16384*2*128

  unsigned short* qkv_ws  = (unsigned short*)d_ws;       // 8192*2048 bf16
  unsigned short* attn_ws = qkv_ws + (size_t)16777216;   // 8192*1536 bf16
  unsigned short* xb      = attn_ws;                     // alias: dead before attn writes
  unsigned short* wqkvb   = attn_ws + (size_t)12582912;  // 2048*1536 bf16
  unsigned short* wob     = wqkvb + (size_t)3145728;     // 1536*1536 bf16
  unsigned short* vt      = wqkvb;                       // alias: wqkvb dead after gemm1
                                                         // (V^T: 8*128*2048 = 2097152 elems)

  // kv caches: reference scatters into the (zero) input caches
  hipMemcpyAsync(kc, kci, (size_t)4194304 * 4, hipMemcpyDeviceToDevice, stream);
  hipMemcpyAsync(vc, vci, (size_t)4194304 * 4, hipMemcpyDeviceToDevice, stream);

  // 0) fp32 -> bf16 pre-convert: x, Wqkv, Wo
  cvt_all<<<dim3(8832), 256, 0, stream>>>(x, Wqkv, Wo, xb, wqkvb, wob);
  // 1) qkv = x @ Wqkv^T + b   (bf16 in, bf16 internal out)
  gemm_bt<false, true><<<dim3(16, 64), 256, 0, stream>>>(
      xb, wqkvb, bqkv, qkv_ws, 8192, 2048, 1536);
  // 2) RoPE q,k in place + scatter k,v into fp32 caches + bf16 V^T
  rope_scatter<<<dim3(4608), 256, 0, stream>>>(qkv_ws, cosb, sinb, slot, kc, vc, vt);
  // 3) causal GQA flash attention (paired q-blocks, phase-interleaved)
  attn_kernel<<<dim3(16, 12, 4), 256, 0, stream>>>(qkv_ws, vt, attn_ws);
  // 4) out = attn @ Wo^T   (bf16 internal in, fp32 out)
  gemm_bt<true, false><<<dim3(12, 64), 256, 0, stream>>>(
      attn_ws, wob, nullptr, out, 8192, 1536, 1536);
}

// Round 14
// 441.098 us; speedup vs baseline: 1.2420x; 1.2420x over previous
//
#include <hip/hip_runtime.h>
#include <hip/hip_bf16.h>
#include <stdint.h>

typedef __attribute__((ext_vector_type(8))) __bf16 bf16x8;
typedef __attribute__((ext_vector_type(4))) float f32x4;

__device__ __forceinline__ float bf2f(unsigned short u) {
  unsigned int x = ((unsigned int)u) << 16;
  float f; __builtin_memcpy(&f, &x, 4); return f;
}
__device__ __forceinline__ unsigned short f2bf(float f) {
  unsigned int x; __builtin_memcpy(&x, &f, 4);
  unsigned int r = x + 0x7fffu + ((x >> 16) & 1u);
  return (unsigned short)(r >> 16);
}
// pack two fp32 -> two bf16 (RNE), low = a, high = b
__device__ __forceinline__ unsigned int pk2(float a, float b) {
  __hip_bfloat162 h = __float22bfloat162_rn(float2{a, b});
  unsigned int u; __builtin_memcpy(&u, &h, 4); return u;
}
__device__ __forceinline__ float fmax3(float a, float b, float c) {
  return fmaxf(fmaxf(a, b), c);  // clang fuses to v_max3_f32
}
// convert 8 consecutive fp32 to 8 bf16 packed in a uint4
__device__ __forceinline__ uint4 cvt8(const float* src) {
  float4 a = *(const float4*)src;
  float4 b = *(const float4*)(src + 4);
  uint4 r;
  r.x = pk2(a.x, a.y); r.y = pk2(a.z, a.w);
  r.z = pk2(b.x, b.y); r.w = pk2(b.z, b.w);
  return r;
}

// async global -> LDS, 16B per lane. LDS dest = wave-uniform base + lane*16.
__device__ __forceinline__ void gload_lds16(const unsigned short* g, unsigned short* l) {
  __builtin_amdgcn_global_load_lds(
      (const __attribute__((address_space(1))) void*)g,
      (__attribute__((address_space(3))) void*)l, 16, 0, 0);
}

// ---------------------------------------------------------------------------
// One-shot fp32 -> bf16 conversion: x (12582912), Wqkv (3145728), Wo (2359296)
// ---------------------------------------------------------------------------
__global__ __launch_bounds__(256) void cvt_all(const float* __restrict__ x,
                                               const float* __restrict__ wqkv,
                                               const float* __restrict__ wo,
                                               unsigned short* __restrict__ xb,
                                               unsigned short* __restrict__ wqkvb,
                                               unsigned short* __restrict__ wob) {
  long i = ((long)blockIdx.x * 256 + threadIdx.x) * 8;
  if (i < 12582912) { *(uint4*)(xb + i) = cvt8(x + i); return; }
  i -= 12582912;
  if (i < 3145728) { *(uint4*)(wqkvb + i) = cvt8(wqkv + i); return; }
  i -= 3145728;
  *(uint4*)(wob + i) = cvt8(wo + i);
}

// ---------------------------------------------------------------------------
// GEMM: C[M,N] = A[M,K] @ W[N,K]^T (+ bias[N]).  (verified rounds 2/4/8/9/11)
// ---------------------------------------------------------------------------
template <bool OUT_F32, bool HAS_BIAS>
__global__ __launch_bounds__(256) void gemm_bt(const unsigned short* __restrict__ A,
                                               const unsigned short* __restrict__ W,
                                               const float* __restrict__ bias,
                                               void* __restrict__ Cv,
                                               int M, int N, int K) {
  __shared__ __align__(16) unsigned short sA[128 * 32];
  __shared__ __align__(16) unsigned short sB[128 * 32];
  const int tid = threadIdx.x;
  const int lane = tid & 63;
  const int w = tid >> 6;
  const long m0 = (long)blockIdx.y * 128;
  const long n0 = (long)blockIdx.x * 128;
  const int wm = (w >> 1) * 64;
  const int wn = (w & 1) * 64;
  const int fr = lane & 15, fq = lane >> 4;

  const int srow = w * 16 + (lane >> 2);
  const int scol = (lane & 3) * 8;
  const unsigned short* Ag = A + m0 * K + (long)srow * K + scol;
  const unsigned short* Wg = W + n0 * K + (long)srow * K + scol;
  const long rstep = 64L * K;
  unsigned short* sAw = sA + w * 512;
  unsigned short* sBw = sB + w * 512;

  f32x4 acc[4][4];
#pragma unroll
  for (int i = 0; i < 4; ++i)
#pragma unroll
    for (int j = 0; j < 4; ++j) acc[i][j] = f32x4{0.f, 0.f, 0.f, 0.f};

  for (int k0 = 0; k0 < K; k0 += 32) {
    __syncthreads();
    gload_lds16(Ag + k0,         sAw);
    gload_lds16(Ag + rstep + k0, sAw + 2048);
    gload_lds16(Wg + k0,         sBw);
    gload_lds16(Wg + rstep + k0, sBw + 2048);
    __syncthreads();
    bf16x8 af[4], bfr[4];
#pragma unroll
    for (int t = 0; t < 4; ++t) {
      af[t]  = *(const bf16x8*)&sA[(wm + t * 16 + fr) * 32 + fq * 8];
      bfr[t] = *(const bf16x8*)&sB[(wn + t * 16 + fr) * 32 + fq * 8];
    }
#pragma unroll
    for (int mt = 0; mt < 4; ++mt)
#pragma unroll
      for (int nt = 0; nt < 4; ++nt)
        acc[mt][nt] = __builtin_amdgcn_mfma_f32_16x16x32_bf16(af[mt], bfr[nt], acc[mt][nt], 0, 0, 0);
  }

#pragma unroll
  for (int nt = 0; nt < 4; ++nt) {
    long n = n0 + wn + nt * 16 + fr;
    float bv = HAS_BIAS ? bias[n] : 0.f;
#pragma unroll
    for (int mt = 0; mt < 4; ++mt)
#pragma unroll
      for (int r = 0; r < 4; ++r) {
        long m = m0 + wm + mt * 16 + fq * 4 + r;
        float v = acc[mt][nt][r] + bv;
        if (OUT_F32)
          ((float*)Cv)[m * N + n] = v;
        else
          ((unsigned short*)Cv)[m * N + n] = f2bf(v);
      }
  }
}

// ---------------------------------------------------------------------------
// RoPE (in-place on bf16 qkv_ws) + fp32 KV cache scatter + bf16 V^T write.
// (verified round 8/9/11)
// ---------------------------------------------------------------------------
__global__ __launch_bounds__(256) void rope_scatter(unsigned short* __restrict__ qkv,
                                                    const float* __restrict__ cosb,
                                                    const float* __restrict__ sinb,
                                                    const int* __restrict__ slot_mapping,
                                                    float* __restrict__ kc,
                                                    float* __restrict__ vc,
                                                    unsigned short* __restrict__ vt) {
  const int u = blockIdx.x * 256 + threadIdx.x;
  if (u < 917504) {
    const int m = u / 112;
    const int g = u - m * 112;
    const int head = g >> 3;
    const int d0 = (g & 7) * 8;
    const int slot = slot_mapping[m];
    const size_t base = (size_t)m * 2048;
    const size_t cbase = (size_t)m * 128;
    const int off = head < 12 ? head * 128 : 1536 + (head - 12) * 128;

    union { uint4 q; unsigned short s[8]; } X1, X2, O1, O2;
    X1.q = *(const uint4*)(qkv + base + off + d0);
    X2.q = *(const uint4*)(qkv + base + off + d0 + 64);
    float c1[8], s1[8], c2[8], s2[8];
    *(float4*)&c1[0] = *(const float4*)(cosb + cbase + d0);
    *(float4*)&c1[4] = *(const float4*)(cosb + cbase + d0 + 4);
    *(float4*)&s1[0] = *(const float4*)(sinb + cbase + d0);
    *(float4*)&s1[4] = *(const float4*)(sinb + cbase + d0 + 4);
    *(float4*)&c2[0] = *(const float4*)(cosb + cbase + d0 + 64);
    *(float4*)&c2[4] = *(const float4*)(cosb + cbase + d0 + 68);
    *(float4*)&s2[0] = *(const float4*)(sinb + cbase + d0 + 64);
    *(float4*)&s2[4] = *(const float4*)(sinb + cbase + d0 + 68);

    float o1[8], o2[8];
#pragma unroll
    for (int j = 0; j < 8; ++j) {
      float x1 = bf2f(X1.s[j]), x2 = bf2f(X2.s[j]);
      o1[j] = x1 * c1[j] - x2 * s1[j];
      o2[j] = x2 * c2[j] + x1 * s2[j];
      O1.s[j] = f2bf(o1[j]);
      O2.s[j] = f2bf(o2[j]);
    }
    *(uint4*)(qkv + base + off + d0) = O1.q;
    *(uint4*)(qkv + base + off + d0 + 64) = O2.q;
    if (head >= 12) {
      float* kp = kc + (size_t)slot * 256 + (head - 12) * 128 + d0;
      *(float4*)(kp)      = *(const float4*)&o1[0];
      *(float4*)(kp + 4)  = *(const float4*)&o1[4];
      *(float4*)(kp + 64) = *(const float4*)&o2[0];
      *(float4*)(kp + 68) = *(const float4*)&o2[4];
    }
  } else {
    const int u2 = u - 917504;
    const int m = u2 & 8191;       // token (consecutive per lane -> coalesced)
    const int g = u2 >> 13;        // 0..31: kvh = g>>4, d0 = (g&15)*8
    const int slot = slot_mapping[m];
    union { uint4 q; unsigned short s[8]; } V;
    V.q = *(const uint4*)(qkv + (size_t)m * 2048 + 1792 + g * 8);
    float vo[8];
#pragma unroll
    for (int j = 0; j < 8; ++j) vo[j] = bf2f(V.s[j]);
    float* vp = vc + (size_t)slot * 256 + g * 8;
    *(float4*)(vp)     = *(const float4*)&vo[0];
    *(float4*)(vp + 4) = *(const float4*)&vo[4];
    // V^T for attention: row = (b*2+kvh)*128 + d, col = s (token within seq)
    const int kvh = g >> 4;
    const int d0 = (g & 15) * 8;
    unsigned short* vtp = vt + ((size_t)((m >> 11) * 2 + kvh) * 128 + d0) * 2048 + (m & 2047);
#pragma unroll
    for (int j = 0; j < 8; ++j) vtp[(size_t)j * 2048] = V.s[j];
  }
}

// ---------------------------------------------------------------------------
// Flash attention, causal, GQA. Swapped QK^T + V^T staging + q-pairing
// (verified r8/r9/r11). Occupancy-first restructure (this version, unmeasured):
//  * SINGLE-buffered K/V (no prefetch): LDS 73 -> 41 KB => 3 blocks/CU,
//    grid 768 = exactly 3 x 256: zero dispatch remainder, zero tail.
//  * 2 barriers/tile; stage latency + serial chains hidden by the other
//    two resident blocks (cross-block TLP), not by intra-block pipelining.
//  * sequential A-then-B process (shared s4/pm temporaries) to keep VGPR
//    under the 3-waves/SIMD cap; __launch_bounds__(256,3) enforces it.
//  * keeps defer-max, packed P-store, max3 tree from r11.
// ---------------------------------------------------------------------------
__global__ __launch_bounds__(256, 3) void attn_kernel(const unsigned short* __restrict__ qkv,
                                                      const unsigned short* __restrict__ vt,
                                                      unsigned short* __restrict__ out) {
  const int qbA = blockIdx.x;       // 0..15
  const int qbB = 31 - qbA;         // 31..16
  const int h = blockIdx.y, b = blockIdx.z;
  const int kvh = h / 6;
  __shared__ __align__(16) unsigned short sK[64 * 128];
  __shared__ __align__(16) unsigned short sV[128 * 64];
  __shared__ __align__(16) unsigned short sP[4][16 * 72];
  const int tid = threadIdx.x, lane = tid & 63, w = tid >> 6;
  const int fr = lane & 15, fq = lane >> 4;
  const float scale = 0.08838834764831845f;
  const float LOG2E = 1.44269504089f;

  bf16x8 qfA[4], qfB[4];  // Q[q = w*16+fr][k = fq*8..+7]
  {
    const unsigned short* qpA =
        qkv + ((size_t)(b * 2048 + qbA * 64 + w * 16 + fr) * 2048 + h * 128 + fq * 8);
    const unsigned short* qpB =
        qkv + ((size_t)(b * 2048 + qbB * 64 + w * 16 + fr) * 2048 + h * 128 + fq * 8);
#pragma unroll
    for (int kt = 0; kt < 4; ++kt) {
      qfA[kt] = *(const bf16x8*)(qpA + kt * 32);
      qfB[kt] = *(const bf16x8*)(qpB + kt * 32);
    }
  }
  float mA = -3.0e38f, lA = 0.f, mB = -3.0e38f, lB = 0.f;
  f32x4 accA[8], accB[8];
#pragma unroll
  for (int i = 0; i < 8; ++i) {
    accA[i] = f32x4{0.f, 0.f, 0.f, 0.f};
    accB[i] = f32x4{0.f, 0.f, 0.f, 0.f};
  }

  auto stage_K = [&](int t) {
    const size_t tok0 = (size_t)(b * 2048 + t * 64);
#pragma unroll
    for (int i = 0; i < 4; ++i) {
      int c = i * 256 + w * 64 + lane;
      int kv = c >> 4, gp = c & 15;
      int g = gp ^ (kv & 7);
      gload_lds16(qkv + (tok0 + kv) * 2048 + 1536 + kvh * 128 + g * 8,
                  sK + i * 2048 + w * 512);
    }
  };
  auto stage_VT = [&](int t) {
    const size_t rowbase = (size_t)((b * 2 + kvh) * 128);
#pragma unroll
    for (int i = 0; i < 4; ++i) {
      int c = i * 256 + w * 64 + lane;
      int d = c >> 3, gp = c & 7;
      int g = gp ^ (d & 7);
      gload_lds16(vt + (rowbase + d) * 2048 + t * 64 + g * 8,
                  sV + i * 2048 + w * 512);
    }
  };

  // phase 1: QK^T (swapped) -> s4
  auto qk = [&](const bf16x8* qf, f32x4* s4) {
#pragma unroll
    for (int ntv = 0; ntv < 4; ++ntv) s4[ntv] = f32x4{0.f, 0.f, 0.f, 0.f};
    __builtin_amdgcn_s_setprio(1);
#pragma unroll
    for (int ntv = 0; ntv < 4; ++ntv) {
      int kvl = ntv * 16 + fr;
      int swz = kvl & 7;
#pragma unroll
      for (int kt = 0; kt < 4; ++kt) {
        bf16x8 kf = *(const bf16x8*)&sK[kvl * 128 + ((kt * 4 + fq) ^ swz) * 8];
        s4[ntv] = __builtin_amdgcn_mfma_f32_16x16x32_bf16(kf, qf[kt], s4[ntv], 0, 0, 0);
      }
    }
    __builtin_amdgcn_s_setprio(0);
  };

  // phase 2: softmax (defer-max).
  auto sm = [&](const f32x4* s4, float& m_i, float& l_i, f32x4* accO,
                float (&pm)[4][4], bool diag) {
    float sc[4][4];
#pragma unroll
    for (int ntv = 0; ntv < 4; ++ntv)
#pragma unroll
      for (int r = 0; r < 4; ++r) {
        float v = s4[ntv][r] * scale;
        if (diag && (ntv * 16 + fq * 4 + r > w * 16 + fr)) v = -1e30f;
        sc[ntv][r] = v;
      }
    float p0 = fmax3(sc[0][0], sc[0][1], sc[0][2]);
    float p1 = fmax3(sc[0][3], sc[1][0], sc[1][1]);
    float p2 = fmax3(sc[1][2], sc[1][3], sc[2][0]);
    float p3 = fmax3(sc[2][1], sc[2][2], sc[2][3]);
    float p4 = fmax3(sc[3][0], sc[3][1], sc[3][2]);
    float mx = fmaxf(fmax3(p0, p1, p2), fmax3(p3, p4, sc[3][3]));
    mx = fmaxf(mx, __shfl_xor(mx, 16));
    mx = fmaxf(mx, __shfl_xor(mx, 32));
    const bool keep = __all(mx <= m_i + 8.0f);
    float al = 1.f;
    if (!keep) {
      float mnew = fmaxf(m_i, mx);
      al = exp2f((m_i - mnew) * LOG2E);
      m_i = mnew;
    }
    float rs4[4];
#pragma unroll
    for (int ntv = 0; ntv < 4; ++ntv) {
#pragma unroll
      for (int r = 0; r < 4; ++r) pm[ntv][r] = exp2f((sc[ntv][r] - m_i) * LOG2E);
      rs4[ntv] = (pm[ntv][0] + pm[ntv][1]) + (pm[ntv][2] + pm[ntv][3]);
    }
    float rs = (rs4[0] + rs4[1]) + (rs4[2] + rs4[3]);
    rs += __shfl_xor(rs, 16);
    rs += __shfl_xor(rs, 32);
    if (!keep) {
      float al4[4];
#pragma unroll
      for (int r = 0; r < 4; ++r) al4[r] = __shfl(al, fq * 4 + r);
#pragma unroll
      for (int n2 = 0; n2 < 8; ++n2)
#pragma unroll
        for (int r = 0; r < 4; ++r) accO[n2][r] *= al4[r];
      l_i = l_i * al + rs;
    } else {
      l_i = l_i + rs;
    }
  };

  // phase 3: packed P store (4x 8B instead of 16x 2B)
  auto store_p = [&](const float (&pm)[4][4]) {
#pragma unroll
    for (int ntv = 0; ntv < 4; ++ntv) {
      uint2 pkd;
      pkd.x = pk2(pm[ntv][0], pm[ntv][1]);
      pkd.y = pk2(pm[ntv][2], pm[ntv][3]);
      *(uint2*)&sP[w][fr * 72 + ntv * 16 + fq * 4] = pkd;
    }
  };

  // phase 4: PV
  auto pv = [&](f32x4* accO) {
    __builtin_amdgcn_s_setprio(1);
#pragma unroll
    for (int kt = 0; kt < 2; ++kt) {
      bf16x8 pf = *(const bf16x8*)&sP[w][fr * 72 + kt * 32 + fq * 8];
#pragma unroll
      for (int n2 = 0; n2 < 8; ++n2) {
        int d = n2 * 16 + fr;
        bf16x8 vf = *(const bf16x8*)&sV[d * 64 + (((kt * 4 + fq) ^ (d & 7)) << 3)];
        accO[n2] = __builtin_amdgcn_mfma_f32_16x16x32_bf16(pf, vf, accO[n2], 0, 0, 0);
      }
    }
    __builtin_amdgcn_s_setprio(0);
  };

  for (int t = 0; t <= qbB; ++t) {
    if (t > 0) __syncthreads();  // all waves done reading previous tile
    stage_K(t);
    stage_VT(t);
    __syncthreads();             // hipcc drains vmcnt before barrier: DMA done

    f32x4 s4[4];
    float pm[4][4];
    if (t <= qbA) {
      qk(qfA, s4);
      sm(s4, mA, lA, accA, pm, t == qbA);
      store_p(pm);
      pv(accA);
    }
    qk(qfB, s4);
    sm(s4, mB, lB, accB, pm, t == qbB);
    store_p(pm);   // same-wave LDS order vs pv(accA)'s reads
    pv(accB);
  }

  auto epilogue = [&](float l_i, const f32x4* accO, int qb) {
    float linv[4];
#pragma unroll
    for (int r = 0; r < 4; ++r) linv[r] = __shfl(l_i, fq * 4 + r);
#pragma unroll
    for (int r = 0; r < 4; ++r) {
      float inv = 1.f / linv[r];
      size_t row = (size_t)(b * 2048 + qb * 64 + w * 16 + fq * 4 + r);
#pragma unroll
      for (int n2 = 0; n2 < 8; ++n2)
        out[row * 1536 + h * 128 + n2 * 16 + fr] = f2bf(accO[n2][r] * inv);
    }
  };
  epilogue(lA, accA, qbA);
  epilogue(lB, accB, qbB);
}

// ---------------------------------------------------------------------------
extern "C" void kernel_launch(void* const* d_in, const int* in_sizes, int n_in,
                              void* d_out, int out_size, void* d_ws, size_t ws_size,
                              hipStream_t stream) {
  const float* x    = (const float*)d_in[0];
  const float* cosb = (const float*)d_in[1];
  const float* sinb = (const float*)d_in[2];
  const float* kci  = (const float*)d_in[3];
  const float* vci  = (const float*)d_in[4];
  const int* slot   = (const int*)d_in[5];
  const float* Wqkv = (const float*)d_in[6];
  const float* bqkv = (const float*)d_in[7];
  const float* Wo   = (const float*)d_in[8];

  float* out = (float*)d_out;
  float* kc  = out + (size_t)12582912;   // 4*2048*1536
  float* vc  = kc + (size_t)4194304;     // 16384*2*128

  unsigned short* qkv_ws  = (unsigned short*)d_ws;       // 8192*2048 bf16
  unsigned short* attn_ws = qkv_ws + (size_t)16777216;   // 8192*1536 bf16
  unsigned short* xb      = attn_ws;                     // alias: dead before attn writes
  unsigned short* wqkvb   = attn_ws + (size_t)12582912;  // 2048*1536 bf16
  unsigned short* wob     = wqkvb + (size_t)3145728;     // 1536*1536 bf16
  unsigned short* vt      = wqkvb;                       // alias: wqkvb dead after gemm1
                                                         // (V^T: 8*128*2048 = 2097152 elems)

  // kv caches: reference scatters into the (zero) input caches
  hipMemcpyAsync(kc, kci, (size_t)4194304 * 4, hipMemcpyDeviceToDevice, stream);
  hipMemcpyAsync(vc, vci, (size_t)4194304 * 4, hipMemcpyDeviceToDevice, stream);

  // 0) fp32 -> bf16 pre-convert: x, Wqkv, Wo
  cvt_all<<<dim3(8832), 256, 0, stream>>>(x, Wqkv, Wo, xb, wqkvb, wob);
  // 1) qkv = x @ Wqkv^T + b   (bf16 in, bf16 internal out)
  gemm_bt<false, true><<<dim3(16, 64), 256, 0, stream>>>(
      xb, wqkvb, bqkv, qkv_ws, 8192, 2048, 1536);
  // 2) RoPE q,k in place + scatter k,v into fp32 caches + bf16 V^T
  rope_scatter<<<dim3(4608), 256, 0, stream>>>(qkv_ws, cosb, sinb, slot, kc, vc, vt);
  // 3) causal GQA flash attention (paired q-blocks, 3 blocks/CU resident)
  attn_kernel<<<dim3(16, 12, 4), 256, 0, stream>>>(qkv_ws, vt, attn_ws);
  // 4) out = attn @ Wo^T   (bf16 internal in, fp32 out)
  gemm_bt<true, false><<<dim3(12, 64), 256, 0, stream>>>(
      attn_ws, wob, nullptr, out, 8192, 1536, 1536);
}